// Round 11
// baseline (864.810 us; speedup 1.0000x reference)
//
#include <hip/hip_runtime.h>

#define N_NODES 100000
#define N_EDGES 1600000
#define F 128

#define SCAN_B 1024
#define SCAN_NB ((N_NODES + SCAN_B - 1) / SCAN_B)   // 98

#define NSHARD 8
#define SHARD_E (N_EDGES / NSHARD)                  // 200000 pairs per shard

#define NCHUNK 256
#define CHUNK_E (N_EDGES / NCHUNK)                  // 6250 edges per chunk
#define HALF_N 50000                                // node-range half (bytes of LDS hist)

#define NSLICE 8                                    // feature slices (1 per XCD)
#define SLICE_C 16                                  // cols per slice (32 B bf16)
#define SROWS 256                                   // rows per spmm tile
#define SBLK ((N_NODES + SROWS - 1) / SROWS)        // 391 tiles per slice
#define NTILE (NSLICE * SBLK)                       // 3128

typedef short bf16x8 __attribute__((ext_vector_type(8)));
typedef float f32x4  __attribute__((ext_vector_type(4)));

union ABFrag {
    bf16x8 v;
    unsigned short u[8];
    uint4  q;
};

__device__ __forceinline__ unsigned short f2bf(float f) {
    unsigned int u = __float_as_uint(f);
    u += 0x7fffu + ((u >> 16) & 1u);   // RNE
    return (unsigned short)(u >> 16);
}
__device__ __forceinline__ float bflo(unsigned int u) {   // low short -> f32
    return __uint_as_float(u << 16);
}
__device__ __forceinline__ float bfhi(unsigned int u) {   // high short -> f32
    return __uint_as_float(u & 0xFFFF0000u);
}

// Physical XCD of this workgroup (0..7 on MI355X, measured learn_hip m09).
__device__ __forceinline__ int xcc_id() {
    unsigned int x;
    asm volatile("s_getreg_b32 %0, hwreg(HW_REG_XCC_ID)" : "=s"(x));
    return (int)(x & 7u);
}

// ---------------- CSR build (zero global atomics; unchanged from R8) --------

__global__ __launch_bounds__(256) void chunk_hist(
    const int* __restrict__ erow, unsigned char* __restrict__ cb) {
    __shared__ unsigned int h[HALF_N / 4];
    const int c    = blockIdx.x >> 1;
    const int half = blockIdx.x & 1;
    const int t    = threadIdx.x;
    for (int i = t; i < HALF_N / 4; i += 256) h[i] = 0;
    __syncthreads();
    const int lo = half * HALF_N;
    for (int e = c * CHUNK_E + t; e < (c + 1) * CHUNK_E; e += 256) {
        const unsigned int d = (unsigned int)(erow[e] - lo);
        if (d < HALF_N) atomicAdd(&h[d >> 2], 1u << ((d & 3u) * 8u));
    }
    __syncthreads();
    unsigned int* dw = (unsigned int*)(cb + (size_t)c * N_NODES + lo);
    for (int i = t; i < HALF_N / 4; i += 256) dw[i] = h[i];
}

__global__ __launch_bounds__(256) void chunk_prefix(
    unsigned char* __restrict__ cb, int* __restrict__ counts) {
    const int t = blockIdx.x * 256 + threadIdx.x;
    if (t >= (N_NODES / 4) * 8) return;
    const int w   = t >> 3;
    const int sub = t & 7;
    const int c0  = sub * (NCHUNK / 8);
    unsigned int v[NCHUNK / 8];
    unsigned int sum = 0;
#pragma unroll
    for (int j = 0; j < NCHUNK / 8; ++j) {
        v[j] = *(const unsigned int*)(cb + (size_t)(c0 + j) * N_NODES + 4 * (size_t)w);
        sum += v[j];
    }
    unsigned int run = sum;
#pragma unroll
    for (int d = 1; d < 8; d <<= 1) {
        unsigned int tmp = __shfl_up(run, d, 8);
        if (sub >= d) run += tmp;
    }
    unsigned int acc = run - sum;
#pragma unroll
    for (int j = 0; j < NCHUNK / 8; ++j) {
        const unsigned int old = v[j];
        *(unsigned int*)(cb + (size_t)(c0 + j) * N_NODES + 4 * (size_t)w) = acc;
        acc += old;
    }
    if (sub == 7) {
        const int n = w * 4;
        counts[n + 0] = run & 255u;
        counts[n + 1] = (run >> 8) & 255u;
        counts[n + 2] = (run >> 16) & 255u;
        counts[n + 3] = run >> 24;
    }
}

__global__ void scan_block_sums(const int* __restrict__ counts, int* __restrict__ bsums) {
    __shared__ int s[SCAN_B];
    const int t = threadIdx.x;
    const int idx = blockIdx.x * SCAN_B + t;
    int v = (idx < N_NODES) ? counts[idx] : 0;
    s[t] = v;
    __syncthreads();
    for (int off = SCAN_B / 2; off > 0; off >>= 1) {
        if (t < off) s[t] += s[t + off];
        __syncthreads();
    }
    if (t == 0) bsums[blockIdx.x] = s[0];
}

__global__ void scan_bsums(const int* __restrict__ bsums, int* __restrict__ boffs) {
    __shared__ int s[128];
    const int t = threadIdx.x;
    int v = (t < SCAN_NB) ? bsums[t] : 0;
    s[t] = v;
    __syncthreads();
    for (int off = 1; off < 128; off <<= 1) {
        int u = (t >= off) ? s[t - off] : 0;
        __syncthreads();
        s[t] += u;
        __syncthreads();
    }
    if (t < SCAN_NB) boffs[t] = s[t] - v;
}

__global__ void scan_final(const int* __restrict__ counts, const int* __restrict__ boffs,
                           int* __restrict__ row_ptr) {
    __shared__ int s[SCAN_B];
    const int t = threadIdx.x;
    const int idx = blockIdx.x * SCAN_B + t;
    int v = (idx < N_NODES) ? counts[idx] : 0;
    s[t] = v;
    __syncthreads();
    for (int off = 1; off < SCAN_B; off <<= 1) {
        int u = (t >= off) ? s[t - off] : 0;
        __syncthreads();
        s[t] += u;
        __syncthreads();
    }
    if (idx < N_NODES) row_ptr[idx] = boffs[blockIdx.x] + s[t] - v;
    if (idx == 0) row_ptr[N_NODES] = N_EDGES;
}

__global__ __launch_bounds__(256) void chunk_rank(
    const int* __restrict__ erow, const int* __restrict__ ecol,
    const float* __restrict__ ew,
    const unsigned char* __restrict__ cb, const int* __restrict__ row_ptr,
    unsigned long long* __restrict__ rec) {
    __shared__ unsigned int h[HALF_N / 4];
    const int c    = blockIdx.x >> 1;
    const int half = blockIdx.x & 1;
    const int t    = threadIdx.x;
    for (int i = t; i < HALF_N / 4; i += 256) h[i] = 0;
    __syncthreads();
    const int lo = half * HALF_N;
    for (int e = c * CHUNK_E + t; e < (c + 1) * CHUNK_E; e += 256) {
        const int dst = erow[e];
        const unsigned int d = (unsigned int)(dst - lo);
        if (d < HALF_N) {
            const unsigned int old = atomicAdd(&h[d >> 2], 1u << ((d & 3u) * 8u));
            const unsigned int lrank = (old >> ((d & 3u) * 8u)) & 255u;
            const unsigned int pos = (unsigned int)row_ptr[dst]
                                   + (unsigned int)cb[(size_t)c * N_NODES + dst]
                                   + lrank;
            const unsigned int colw = ((unsigned int)ecol[e] << 15)
                                    | (unsigned int)f2bf(ew[e]);
            rec[e] = ((unsigned long long)pos << 32) | colw;
        }
    }
}

__global__ __launch_bounds__(256) void csr_fill_sharded(
    const unsigned long long* __restrict__ rec,
    unsigned int* __restrict__ pairs) {
    const int shard = blockIdx.x & (NSHARD - 1);
    const int e = (blockIdx.x >> 3) * 256 + threadIdx.x;
    const unsigned long long v = rec[e];
    const unsigned int pos = (unsigned int)(v >> 32);
    if ((unsigned int)(pos - (unsigned int)(shard * SHARD_E)) < (unsigned int)SHARD_E) {
        pairs[pos] = (unsigned int)v;
    }
}

// ---------------- W^T -> bf16 (all three weights, one dispatch) -------------
__global__ void transpose_w_bf16(const float* __restrict__ W1,
                                 const float* __restrict__ W2,
                                 const float* __restrict__ W3,
                                 unsigned short* __restrict__ Wt1,
                                 unsigned short* __restrict__ Wt2,
                                 unsigned short* __restrict__ Wt3) {
    const int g = blockIdx.x >> 6;
    const int i = (blockIdx.x & 63) * 256 + threadIdx.x;
    const int n = i >> 7;
    const int k = i & 127;
    const float* W = (g == 0) ? W1 : (g == 1) ? W2 : W3;
    unsigned short* Wt = (g == 0) ? Wt1 : (g == 1) ? Wt2 : Wt3;
    Wt[i] = f2bf(W[k * F + n]);
}

// ---------------- SLICED layout (R10, correctness-verified) -----------------
// Intermediates stored [NSLICE][N][SLICE_C] bf16 (3.2 MB per slice).
// R10 lesson: blockIdx&7 does NOT pin to XCDs (FETCH 220 MB refuted it), and
// nontemporal 16B stores don't write-combine (WRITE 4x). Now: read the REAL
// XCD via HW_REG_XCC_ID, claim row-tiles from a per-XCD ticket so each XCD
// gathers only its own L2-resident slice; normal stores (adjacent lanes fill
// full lines). Cleanup kernel (stream-ordered) re-processes any unclaimed
// tile -> correctness never depends on dispatch/XCD assignment (G16);
// duplicate processing is idempotent.

// ---------------- MFMA GEMM, layer 1 (fp32 in, sliced out) ------------------
__global__ __launch_bounds__(256) void gemm_mfma(
    const float* __restrict__ Xf,
    const unsigned short* __restrict__ Wt,   // bf16 W^T [128][128]
    unsigned short* __restrict__ Ysl)        // sliced [8][N][16], raw X@W
{
    __shared__ unsigned short Wl[4 * 8 * 64 * 8];   // 32 KB, frag order

    const int tid  = threadIdx.x;
    const int wave = tid >> 6;
    const int lane = tid & 63;

    for (int s = tid; s < 2048; s += 256) {
        const int ln  = s & 63;
        const int ntk = s >> 6;
        const int nt  = ntk & 7;
        const int kt  = ntk >> 3;
        const int n   = nt * 16 + (ln & 15);
        const int k   = kt * 32 + (ln >> 4) * 8;
        *(uint4*)(&Wl[s * 8]) = *(const uint4*)(Wt + n * F + k);
    }
    __syncthreads();

    const int m     = blockIdx.x * 64 + wave * 16 + (lane & 15);
    const bool mval = (m < N_NODES);
    const int kq    = (lane >> 4) * 8;

    f32x4 acc[8] = {};

#pragma unroll
    for (int kt = 0; kt < 4; ++kt) {
        ABFrag a;
        if (mval) {
            const float* p = Xf + (size_t)m * F + kt * 32 + kq;
            const float4 u0 = *(const float4*)p;
            const float4 u1 = *(const float4*)(p + 4);
            a.u[0] = f2bf(u0.x); a.u[1] = f2bf(u0.y);
            a.u[2] = f2bf(u0.z); a.u[3] = f2bf(u0.w);
            a.u[4] = f2bf(u1.x); a.u[5] = f2bf(u1.y);
            a.u[6] = f2bf(u1.z); a.u[7] = f2bf(u1.w);
        } else {
            a.q = make_uint4(0, 0, 0, 0);
        }
#pragma unroll
        for (int nt = 0; nt < 8; ++nt) {
            ABFrag b;
            b.q = *(const uint4*)(&Wl[((kt * 8 + nt) * 64 + lane) * 8]);
            acc[nt] = __builtin_amdgcn_mfma_f32_16x16x32_bf16(a.v, b.v, acc[nt], 0, 0, 0);
        }
    }

    const int rbase = blockIdx.x * 64 + wave * 16 + (lane >> 4) * 4;
    const int cbase = lane & 15;
#pragma unroll
    for (int r = 0; r < 4; ++r) {
        const int row = rbase + r;
        if (row < N_NODES) {
#pragma unroll
            for (int nt = 0; nt < 8; ++nt) {
                Ysl[((size_t)nt * N_NODES + row) * SLICE_C + cbase] = f2bf(acc[nt][r]);
            }
        }
    }
}

// ---------------- MFMA GEMM, layers 2/3 (sliced relu'd bf16 in, sliced out) -
__global__ __launch_bounds__(256) void gemm_mfma_sl(
    const unsigned short* __restrict__ Asl,  // sliced [8][N][16], relu'd
    const unsigned short* __restrict__ Wt,
    unsigned short* __restrict__ Ysl)        // sliced [8][N][16], raw X@W
{
    __shared__ unsigned short Wl[4 * 8 * 64 * 8];

    const int tid  = threadIdx.x;
    const int wave = tid >> 6;
    const int lane = tid & 63;

    for (int s = tid; s < 2048; s += 256) {
        const int ln  = s & 63;
        const int ntk = s >> 6;
        const int nt  = ntk & 7;
        const int kt  = ntk >> 3;
        const int n   = nt * 16 + (ln & 15);
        const int k   = kt * 32 + (ln >> 4) * 8;
        *(uint4*)(&Wl[s * 8]) = *(const uint4*)(Wt + n * F + k);
    }
    __syncthreads();

    const int m     = blockIdx.x * 64 + wave * 16 + (lane & 15);
    const bool mval = (m < N_NODES);
    const int kq    = (lane >> 4) * 8;

    f32x4 acc[8] = {};

#pragma unroll
    for (int kt = 0; kt < 4; ++kt) {
        ABFrag a;
        if (mval) {
            const int c = kt * 32 + kq;          // multiple of 8
            a.q = *(const uint4*)(Asl + ((size_t)(c >> 4) * N_NODES + m) * SLICE_C + (c & 15));
        } else {
            a.q = make_uint4(0, 0, 0, 0);
        }
#pragma unroll
        for (int nt = 0; nt < 8; ++nt) {
            ABFrag b;
            b.q = *(const uint4*)(&Wl[((kt * 8 + nt) * 64 + lane) * 8]);
            acc[nt] = __builtin_amdgcn_mfma_f32_16x16x32_bf16(a.v, b.v, acc[nt], 0, 0, 0);
        }
    }

    const int rbase = blockIdx.x * 64 + wave * 16 + (lane >> 4) * 4;
    const int cbase = lane & 15;
#pragma unroll
    for (int r = 0; r < 4; ++r) {
        const int row = rbase + r;
        if (row < N_NODES) {
#pragma unroll
            for (int nt = 0; nt < 8; ++nt) {
                Ysl[((size_t)nt * N_NODES + row) * SLICE_C + cbase] = f2bf(acc[nt][r]);
            }
        }
    }
}

// ---------------- SpMM tile body (shared by affine + cleanup) ---------------
__device__ __forceinline__ void spmm_tile(
    int sl, int rowblk,
    const unsigned short* __restrict__ Xsl,
    const int* __restrict__ row_ptr,
    const unsigned int* __restrict__ pairs,
    unsigned short* __restrict__ Ysl,
    float* __restrict__ Of,
    int final_mode)
{
    const int row = rowblk * SROWS + (int)threadIdx.x;
    if (row >= N_NODES) return;

    const unsigned short* Xs = Xsl + (size_t)sl * N_NODES * SLICE_C;
    const int beg = row_ptr[row];
    const int end = row_ptr[row + 1];

    float a[16] = {};
    int i = beg;
    for (; i + 1 < end; i += 2) {
        const unsigned int p0 = pairs[i];
        const unsigned int p1 = pairs[i + 1];
        const unsigned short* r0 = Xs + (size_t)(p0 >> 15) * SLICE_C;
        const unsigned short* r1 = Xs + (size_t)(p1 >> 15) * SLICE_C;
        const uint4 u0 = *(const uint4*)r0;
        const uint4 u1 = *(const uint4*)(r0 + 8);
        const uint4 u2 = *(const uint4*)r1;
        const uint4 u3 = *(const uint4*)(r1 + 8);
        const float w0 = bflo(p0 & 0x7FFFu);
        const float w1 = bflo(p1 & 0x7FFFu);
        a[0]  += w0 * bflo(u0.x); a[1]  += w0 * bfhi(u0.x);
        a[2]  += w0 * bflo(u0.y); a[3]  += w0 * bfhi(u0.y);
        a[4]  += w0 * bflo(u0.z); a[5]  += w0 * bfhi(u0.z);
        a[6]  += w0 * bflo(u0.w); a[7]  += w0 * bfhi(u0.w);
        a[8]  += w0 * bflo(u1.x); a[9]  += w0 * bfhi(u1.x);
        a[10] += w0 * bflo(u1.y); a[11] += w0 * bfhi(u1.y);
        a[12] += w0 * bflo(u1.z); a[13] += w0 * bfhi(u1.z);
        a[14] += w0 * bflo(u1.w); a[15] += w0 * bfhi(u1.w);
        a[0]  += w1 * bflo(u2.x); a[1]  += w1 * bfhi(u2.x);
        a[2]  += w1 * bflo(u2.y); a[3]  += w1 * bfhi(u2.y);
        a[4]  += w1 * bflo(u2.z); a[5]  += w1 * bfhi(u2.z);
        a[6]  += w1 * bflo(u2.w); a[7]  += w1 * bfhi(u2.w);
        a[8]  += w1 * bflo(u3.x); a[9]  += w1 * bfhi(u3.x);
        a[10] += w1 * bflo(u3.y); a[11] += w1 * bfhi(u3.y);
        a[12] += w1 * bflo(u3.z); a[13] += w1 * bfhi(u3.z);
        a[14] += w1 * bflo(u3.w); a[15] += w1 * bfhi(u3.w);
    }
    if (i < end) {
        const unsigned int p0 = pairs[i];
        const unsigned short* r0 = Xs + (size_t)(p0 >> 15) * SLICE_C;
        const uint4 u0 = *(const uint4*)r0;
        const uint4 u1 = *(const uint4*)(r0 + 8);
        const float w0 = bflo(p0 & 0x7FFFu);
        a[0]  += w0 * bflo(u0.x); a[1]  += w0 * bfhi(u0.x);
        a[2]  += w0 * bflo(u0.y); a[3]  += w0 * bfhi(u0.y);
        a[4]  += w0 * bflo(u0.z); a[5]  += w0 * bfhi(u0.z);
        a[6]  += w0 * bflo(u0.w); a[7]  += w0 * bfhi(u0.w);
        a[8]  += w0 * bflo(u1.x); a[9]  += w0 * bfhi(u1.x);
        a[10] += w0 * bflo(u1.y); a[11] += w0 * bfhi(u1.y);
        a[12] += w0 * bflo(u1.z); a[13] += w0 * bfhi(u1.z);
        a[14] += w0 * bflo(u1.w); a[15] += w0 * bfhi(u1.w);
    }

#pragma unroll
    for (int j = 0; j < 16; ++j) a[j] = fmaxf(a[j], 0.f);

    if (final_mode) {
        // cols [sl*16, +16): one full 64 B f32 line per lane, normal stores.
        float* p = Of + (size_t)row * F + sl * SLICE_C;
        float4 o0 = {a[0], a[1], a[2], a[3]};
        float4 o1 = {a[4], a[5], a[6], a[7]};
        float4 o2 = {a[8], a[9], a[10], a[11]};
        float4 o3 = {a[12], a[13], a[14], a[15]};
        *(float4*)p = o0;
        *(float4*)(p + 4) = o1;
        *(float4*)(p + 8) = o2;
        *(float4*)(p + 12) = o3;
    } else {
        // 32 B per lane, adjacent lanes = adjacent rows -> full lines combine.
        unsigned short* y = Ysl + ((size_t)sl * N_NODES + row) * SLICE_C;
        uint4 o0, o1;
        o0.x = (unsigned int)f2bf(a[0])  | ((unsigned int)f2bf(a[1])  << 16);
        o0.y = (unsigned int)f2bf(a[2])  | ((unsigned int)f2bf(a[3])  << 16);
        o0.z = (unsigned int)f2bf(a[4])  | ((unsigned int)f2bf(a[5])  << 16);
        o0.w = (unsigned int)f2bf(a[6])  | ((unsigned int)f2bf(a[7])  << 16);
        o1.x = (unsigned int)f2bf(a[8])  | ((unsigned int)f2bf(a[9])  << 16);
        o1.y = (unsigned int)f2bf(a[10]) | ((unsigned int)f2bf(a[11]) << 16);
        o1.z = (unsigned int)f2bf(a[12]) | ((unsigned int)f2bf(a[13]) << 16);
        o1.w = (unsigned int)f2bf(a[14]) | ((unsigned int)f2bf(a[15]) << 16);
        *(uint4*)y = o0;
        *(uint4*)(y + 8) = o1;
    }
}

// XCD-affine pass: slice = this block's physical XCD; row-tile from a
// per-XCD ticket. Tiles claimed here are flagged done (flag visibility to the
// cleanup kernel is guaranteed by the kernel boundary on the same stream).
__global__ __launch_bounds__(256) void spmm_affine(
    const unsigned short* __restrict__ Xsl,
    const int* __restrict__ row_ptr,
    const unsigned int* __restrict__ pairs,
    unsigned short* __restrict__ Ysl,
    float* __restrict__ Of,
    int final_mode,
    int* __restrict__ tick, int* __restrict__ done)
{
    __shared__ int s_t, s_x;
    if (threadIdx.x == 0) {
        const int xcd = xcc_id();
        int t = SBLK;
        if (*(volatile int*)&tick[xcd] < SBLK)   // peek (stale-low is safe)
            t = atomicAdd(&tick[xcd], 1);
        if (t < SBLK) done[xcd * SBLK + t] = 1;  // claimed; stores complete at kernel end
        s_t = t; s_x = xcd;
    }
    __syncthreads();
    const int t = s_t, xcd = s_x;
    if (t >= SBLK) return;
    spmm_tile(xcd, t, Xsl, row_ptr, pairs, Ysl, Of, final_mode);
}

// Cleanup: any tile not claimed by the affine pass (uneven block->XCD
// distribution) is processed here; normally a pure flag scan.
__global__ __launch_bounds__(256) void spmm_cleanup(
    const unsigned short* __restrict__ Xsl,
    const int* __restrict__ row_ptr,
    const unsigned int* __restrict__ pairs,
    unsigned short* __restrict__ Ysl,
    float* __restrict__ Of,
    int final_mode,
    const int* __restrict__ done)
{
    const int b = blockIdx.x;
    if (done[b]) return;
    spmm_tile(b / SBLK, b % SBLK, Xsl, row_ptr, pairs, Ysl, Of, final_mode);
}

// ---------------- launch ----------------

extern "C" void kernel_launch(void* const* d_in, const int* in_sizes, int n_in,
                              void* d_out, int out_size, void* d_ws, size_t ws_size,
                              hipStream_t stream) {
    const float* x    = (const float*)d_in[0];
    const int*   erow = (const int*)d_in[1];
    const int*   ecol = (const int*)d_in[2];
    const float* ew   = (const float*)d_in[3];
    const float* w1   = (const float*)d_in[4];
    const float* w2   = (const float*)d_in[5];
    const float* w3   = (const float*)d_in[6];
    float* out = (float*)d_out;

    char* ws = (char*)d_ws;
    size_t off = 0;
    auto alloc = [&](size_t bytes) -> char* {
        char* p = ws + off;
        off += (bytes + 255) & ~(size_t)255;
        return p;
    };
    unsigned short* bufA = (unsigned short*)alloc((size_t)N_NODES * F * 2); // 25.6 MB sliced
    unsigned short* bufB = (unsigned short*)alloc((size_t)N_NODES * F * 2); // 25.6 MB sliced
    unsigned int* pairs  = (unsigned int*)alloc((size_t)N_EDGES * 4);       // 6.4 MB
    int* counts  = (int*)alloc((size_t)N_NODES * sizeof(int));
    int* row_ptr = (int*)alloc(((size_t)N_NODES + 1) * sizeof(int));
    int* bsums   = (int*)alloc((size_t)SCAN_NB * sizeof(int));
    int* boffs   = (int*)alloc((size_t)SCAN_NB * sizeof(int));
    int* tick3   = (int*)alloc((size_t)3 * 8 * sizeof(int));
    int* done3   = (int*)alloc((size_t)3 * NTILE * sizeof(int));
    unsigned short* wt1 = (unsigned short*)alloc((size_t)F * F * 2);
    unsigned short* wt2 = (unsigned short*)alloc((size_t)F * F * 2);
    unsigned short* wt3 = (unsigned short*)alloc((size_t)F * F * 2);

    // Aliasing (CSR-build scratch dies before the GEMM/SpMM chain):
    //  - cb (25.6 MB) in bufA: consumed by chunk_rank before g1 writes bufA.
    //  - rec (12.8 MB) in bufB: consumed by csr_fill_sharded before s1 writes bufB.
    unsigned char* cb = (unsigned char*)bufA;
    unsigned long long* rec = (unsigned long long*)bufB;

    hipMemsetAsync(tick3, 0, (size_t)3 * 8 * sizeof(int), stream);
    hipMemsetAsync(done3, 0, (size_t)3 * NTILE * sizeof(int), stream);

    // --- CSR build (once; reused by all 3 layers). Zero global atomics. ---
    chunk_hist<<<NCHUNK * 2, 256, 0, stream>>>(erow, cb);
    chunk_prefix<<<((N_NODES / 4) * 8 + 255) / 256, 256, 0, stream>>>(cb, counts);
    scan_block_sums<<<SCAN_NB, SCAN_B, 0, stream>>>(counts, bsums);
    scan_bsums<<<1, 128, 0, stream>>>(bsums, boffs);
    scan_final<<<SCAN_NB, SCAN_B, 0, stream>>>(counts, boffs, row_ptr);
    chunk_rank<<<NCHUNK * 2, 256, 0, stream>>>(erow, ecol, ew, cb, row_ptr, rec);
    csr_fill_sharded<<<(N_EDGES / 256) * NSHARD, 256, 0, stream>>>(rec, pairs);

    // --- Weight transposes to bf16 (single dispatch) ---
    transpose_w_bf16<<<192, 256, 0, stream>>>(w1, w2, w3, wt1, wt2, wt3);

    const int ggrid = (N_NODES + 63) / 64;   // 1563

    // g1: bufA_sl = x @ w1 (raw)
    gemm_mfma<<<ggrid, 256, 0, stream>>>(x, wt1, bufA);
    // s1: bufB_sl = relu(spmm(bufA_sl))
    spmm_affine<<<NTILE, 256, 0, stream>>>(bufA, row_ptr, pairs, bufB, nullptr, 0,
                                           tick3 + 0, done3 + 0);
    spmm_cleanup<<<NTILE, 256, 0, stream>>>(bufA, row_ptr, pairs, bufB, nullptr, 0,
                                            done3 + 0);
    // g2: bufA_sl = bufB_sl @ w2
    gemm_mfma_sl<<<ggrid, 256, 0, stream>>>(bufB, wt2, bufA);
    // s2: bufB_sl = relu(spmm(bufA_sl))
    spmm_affine<<<NTILE, 256, 0, stream>>>(bufA, row_ptr, pairs, bufB, nullptr, 0,
                                           tick3 + 8, done3 + NTILE);
    spmm_cleanup<<<NTILE, 256, 0, stream>>>(bufA, row_ptr, pairs, bufB, nullptr, 0,
                                            done3 + NTILE);
    // g3: bufA_sl = bufB_sl @ w3
    gemm_mfma_sl<<<ggrid, 256, 0, stream>>>(bufB, wt3, bufA);
    // s3: out = relu(spmm(bufA_sl)) f32
    spmm_affine<<<NTILE, 256, 0, stream>>>(bufA, row_ptr, pairs, nullptr, out, 1,
                                           tick3 + 16, done3 + 2 * NTILE);
    spmm_cleanup<<<NTILE, 256, 0, stream>>>(bufA, row_ptr, pairs, nullptr, out, 1,
                                            done3 + 2 * NTILE);
}

// Round 12
// 428.711 us; speedup vs baseline: 2.0172x; 2.0172x over previous
//
#include <hip/hip_runtime.h>

#define N_NODES 100000
#define N_EDGES 1600000
#define F 128

#define SCAN_B 1024
#define SCAN_NB ((N_NODES + SCAN_B - 1) / SCAN_B)   // 98

#define NSHARD 4
#define NSHARD_SHIFT 2
#define SHARD_E (N_EDGES / NSHARD)                  // 400000 pairs = 1.6 MB window

#define NCHUNK 256
#define CHUNK_E (N_EDGES / NCHUNK)                  // 6250 edges per chunk
#define HALF_N 50000                                // node-range half (bytes of LDS hist)

typedef short bf16x8 __attribute__((ext_vector_type(8)));
typedef float f32x4  __attribute__((ext_vector_type(4)));

union ABFrag {
    bf16x8 v;
    unsigned short u[8];
    uint4  q;
};

__device__ __forceinline__ unsigned short f2bf(float f) {
    unsigned int u = __float_as_uint(f);
    u += 0x7fffu + ((u >> 16) & 1u);   // RNE
    return (unsigned short)(u >> 16);
}
__device__ __forceinline__ float bflo(unsigned int u) {   // low short -> f32
    return __uint_as_float(u << 16);
}
__device__ __forceinline__ float bfhi(unsigned int u) {   // high short -> f32
    return __uint_as_float(u & 0xFFFF0000u);
}

// Gather-accumulate over one CSR row, 16 lanes x 8 cols per lane.
// Unroll x4 (R6: +8%); x8 would cross the 64-VGPR occupancy cliff.
// STRUCTURAL NOTE (R7/R10/R11): the gather delivers ~5.5 TB/s of random 256B
// row-fetches — at the fabric/L3 random-access ceiling. Refuted by counters:
// degree balancing (R7, net-zero), mod-8 slice pinning (R10, FETCH 220MB),
// HW_REG_XCC_ID-affine slice pinning (R11, FETCH 314MB). Do not retry
// scheduling fixes; only logical-byte reduction could help (accuracy-risky).
__device__ __forceinline__ void gather_accum(
    const unsigned short* __restrict__ Xb,
    const unsigned int* __restrict__ pairs,
    int beg, int end, int l16, float (&a)[8]) {
    int i = beg;
    for (; i + 3 < end; i += 4) {
        const unsigned int p0 = pairs[i], p1 = pairs[i + 1];
        const unsigned int p2 = pairs[i + 2], p3 = pairs[i + 3];
        const uint4 v0 = *(const uint4*)(Xb + (size_t)(p0 >> 15) * F + l16 * 8);
        const uint4 v1 = *(const uint4*)(Xb + (size_t)(p1 >> 15) * F + l16 * 8);
        const uint4 v2 = *(const uint4*)(Xb + (size_t)(p2 >> 15) * F + l16 * 8);
        const uint4 v3 = *(const uint4*)(Xb + (size_t)(p3 >> 15) * F + l16 * 8);
        const float w0 = bflo(p0 & 0x7FFFu);
        const float w1 = bflo(p1 & 0x7FFFu);
        const float w2 = bflo(p2 & 0x7FFFu);
        const float w3 = bflo(p3 & 0x7FFFu);
        a[0] += w0 * bflo(v0.x); a[1] += w0 * bfhi(v0.x);
        a[2] += w0 * bflo(v0.y); a[3] += w0 * bfhi(v0.y);
        a[4] += w0 * bflo(v0.z); a[5] += w0 * bfhi(v0.z);
        a[6] += w0 * bflo(v0.w); a[7] += w0 * bfhi(v0.w);
        a[0] += w1 * bflo(v1.x); a[1] += w1 * bfhi(v1.x);
        a[2] += w1 * bflo(v1.y); a[3] += w1 * bfhi(v1.y);
        a[4] += w1 * bflo(v1.z); a[5] += w1 * bfhi(v1.z);
        a[6] += w1 * bflo(v1.w); a[7] += w1 * bfhi(v1.w);
        a[0] += w2 * bflo(v2.x); a[1] += w2 * bfhi(v2.x);
        a[2] += w2 * bflo(v2.y); a[3] += w2 * bfhi(v2.y);
        a[4] += w2 * bflo(v2.z); a[5] += w2 * bfhi(v2.z);
        a[6] += w2 * bflo(v2.w); a[7] += w2 * bfhi(v2.w);
        a[0] += w3 * bflo(v3.x); a[1] += w3 * bfhi(v3.x);
        a[2] += w3 * bflo(v3.y); a[3] += w3 * bfhi(v3.y);
        a[4] += w3 * bflo(v3.z); a[5] += w3 * bfhi(v3.z);
        a[6] += w3 * bflo(v3.w); a[7] += w3 * bfhi(v3.w);
    }
    for (; i < end; ++i) {
        const unsigned int p0 = pairs[i];
        const uint4 v0 = *(const uint4*)(Xb + (size_t)(p0 >> 15) * F + l16 * 8);
        const float w0 = bflo(p0 & 0x7FFFu);
        a[0] += w0 * bflo(v0.x); a[1] += w0 * bfhi(v0.x);
        a[2] += w0 * bflo(v0.y); a[3] += w0 * bfhi(v0.y);
        a[4] += w0 * bflo(v0.z); a[5] += w0 * bfhi(v0.z);
        a[6] += w0 * bflo(v0.w); a[7] += w0 * bfhi(v0.w);
    }
}

// ---------------- CSR build (zero global atomics) ----------------
// Degrees are Poisson(16): max ~45 <= 255, so every per-node count/rank fits a
// byte. Chunk-local byte histograms live in LDS (atomics stay on-chip).

// Phase A: per-(chunk,half) LDS byte histogram -> cb[c][n].
__global__ __launch_bounds__(256) void chunk_hist(
    const int* __restrict__ erow, unsigned char* __restrict__ cb) {
    __shared__ unsigned int h[HALF_N / 4];
    const int c    = blockIdx.x >> 1;
    const int half = blockIdx.x & 1;
    const int t    = threadIdx.x;
    for (int i = t; i < HALF_N / 4; i += 256) h[i] = 0;
    __syncthreads();
    const int lo = half * HALF_N;
    for (int e = c * CHUNK_E + t; e < (c + 1) * CHUNK_E; e += 256) {
        const unsigned int d = (unsigned int)(erow[e] - lo);
        if (d < HALF_N) atomicAdd(&h[d >> 2], 1u << ((d & 3u) * 8u));
    }
    __syncthreads();
    unsigned int* dw = (unsigned int*)(cb + (size_t)c * N_NODES + lo);
    for (int i = t; i < HALF_N / 4; i += 256) dw[i] = h[i];
}

// Phase B: vertical exclusive prefix over chunks, in place (cb counts -> cb
// bases), packed-byte add (carry-free for degree<=255). 8 lanes per u32 word.
__global__ __launch_bounds__(256) void chunk_prefix(
    unsigned char* __restrict__ cb, int* __restrict__ counts) {
    const int t = blockIdx.x * 256 + threadIdx.x;
    if (t >= (N_NODES / 4) * 8) return;
    const int w   = t >> 3;          // u32 word index (4 nodes)
    const int sub = t & 7;           // chunk-group lane
    const int c0  = sub * (NCHUNK / 8);
    unsigned int v[NCHUNK / 8];
    unsigned int sum = 0;
#pragma unroll
    for (int j = 0; j < NCHUNK / 8; ++j) {
        v[j] = *(const unsigned int*)(cb + (size_t)(c0 + j) * N_NODES + 4 * (size_t)w);
        sum += v[j];
    }
    unsigned int run = sum;          // inclusive scan across sub (width 8)
#pragma unroll
    for (int d = 1; d < 8; d <<= 1) {
        unsigned int tmp = __shfl_up(run, d, 8);
        if (sub >= d) run += tmp;
    }
    unsigned int acc = run - sum;    // exclusive base for this lane's chunks
#pragma unroll
    for (int j = 0; j < NCHUNK / 8; ++j) {
        const unsigned int old = v[j];
        *(unsigned int*)(cb + (size_t)(c0 + j) * N_NODES + 4 * (size_t)w) = acc;
        acc += old;
    }
    if (sub == 7) {                  // run = total degree of the 4 nodes
        const int n = w * 4;
        counts[n + 0] = run & 255u;
        counts[n + 1] = (run >> 8) & 255u;
        counts[n + 2] = (run >> 16) & 255u;
        counts[n + 3] = run >> 24;
    }
}

__global__ void scan_block_sums(const int* __restrict__ counts, int* __restrict__ bsums) {
    __shared__ int s[SCAN_B];
    const int t = threadIdx.x;
    const int idx = blockIdx.x * SCAN_B + t;
    int v = (idx < N_NODES) ? counts[idx] : 0;
    s[t] = v;
    __syncthreads();
    for (int off = SCAN_B / 2; off > 0; off >>= 1) {
        if (t < off) s[t] += s[t + off];
        __syncthreads();
    }
    if (t == 0) bsums[blockIdx.x] = s[0];
}

__global__ void scan_bsums(const int* __restrict__ bsums, int* __restrict__ boffs) {
    __shared__ int s[128];
    const int t = threadIdx.x;
    int v = (t < SCAN_NB) ? bsums[t] : 0;
    s[t] = v;
    __syncthreads();
    for (int off = 1; off < 128; off <<= 1) {
        int u = (t >= off) ? s[t - off] : 0;
        __syncthreads();
        s[t] += u;
        __syncthreads();
    }
    if (t < SCAN_NB) boffs[t] = s[t] - v;
}

__global__ void scan_final(const int* __restrict__ counts, const int* __restrict__ boffs,
                           int* __restrict__ row_ptr) {
    __shared__ int s[SCAN_B];
    const int t = threadIdx.x;
    const int idx = blockIdx.x * SCAN_B + t;
    int v = (idx < N_NODES) ? counts[idx] : 0;
    s[t] = v;
    __syncthreads();
    for (int off = 1; off < SCAN_B; off <<= 1) {
        int u = (t >= off) ? s[t - off] : 0;
        __syncthreads();
        s[t] += u;
        __syncthreads();
    }
    if (idx < N_NODES) row_ptr[idx] = boffs[blockIdx.x] + s[t] - v;
    if (idx == 0) row_ptr[N_NODES] = N_EDGES;
}

// Phase D: replay LDS fetch-add for intra-chunk rank; emit absolute position.
__global__ __launch_bounds__(256) void chunk_rank(
    const int* __restrict__ erow, const int* __restrict__ ecol,
    const float* __restrict__ ew,
    const unsigned char* __restrict__ cb, const int* __restrict__ row_ptr,
    unsigned long long* __restrict__ rec) {
    __shared__ unsigned int h[HALF_N / 4];
    const int c    = blockIdx.x >> 1;
    const int half = blockIdx.x & 1;
    const int t    = threadIdx.x;
    for (int i = t; i < HALF_N / 4; i += 256) h[i] = 0;
    __syncthreads();
    const int lo = half * HALF_N;
    for (int e = c * CHUNK_E + t; e < (c + 1) * CHUNK_E; e += 256) {
        const int dst = erow[e];
        const unsigned int d = (unsigned int)(dst - lo);
        if (d < HALF_N) {
            const unsigned int old = atomicAdd(&h[d >> 2], 1u << ((d & 3u) * 8u));
            const unsigned int lrank = (old >> ((d & 3u) * 8u)) & 255u;
            const unsigned int pos = (unsigned int)row_ptr[dst]
                                   + (unsigned int)cb[(size_t)c * N_NODES + dst]
                                   + lrank;
            const unsigned int colw = ((unsigned int)ecol[e] << 15)
                                    | (unsigned int)f2bf(ew[e]);
            rec[e] = ((unsigned long long)pos << 32) | colw;
        }
    }
}

// Phase E: range-sharded scatter on pos. Each shard's 1.6 MB pairs window is
// L2-resident wherever the block runs, so the ~16 writes per 64B line combine
// before one eviction (R2-verified mechanism). NSHARD 8->4 (R11): halves the
// rec re-read stream (102->51 MB) while keeping the window L2-fit.
__global__ __launch_bounds__(256) void csr_fill_sharded(
    const unsigned long long* __restrict__ rec,
    unsigned int* __restrict__ pairs) {
    const int shard = blockIdx.x & (NSHARD - 1);
    const int e = (blockIdx.x >> NSHARD_SHIFT) * 256 + threadIdx.x;
    const unsigned long long v = rec[e];
    const unsigned int pos = (unsigned int)(v >> 32);
    if ((unsigned int)(pos - (unsigned int)(shard * SHARD_E)) < (unsigned int)SHARD_E) {
        pairs[pos] = (unsigned int)v;
    }
}

// ---------------- W^T -> bf16 (all three weights, one dispatch) -------------
__global__ void transpose_w_bf16(const float* __restrict__ W1,
                                 const float* __restrict__ W2,
                                 const float* __restrict__ W3,
                                 unsigned short* __restrict__ Wt1,
                                 unsigned short* __restrict__ Wt2,
                                 unsigned short* __restrict__ Wt3) {
    const int g = blockIdx.x >> 6;                  // 0,1,2
    const int i = (blockIdx.x & 63) * 256 + threadIdx.x;   // 0..16383
    const int n = i >> 7;
    const int k = i & 127;
    const float* W = (g == 0) ? W1 : (g == 1) ? W2 : W3;
    unsigned short* Wt = (g == 0) ? Wt1 : (g == 1) ? Wt2 : Wt3;
    Wt[i] = f2bf(W[k * F + n]);                     // Wt[n][k] = W[k][n]
}

// ---------------- MFMA bf16 GEMM (layer 1 only: fp32 in, no relu) ----------
__global__ __launch_bounds__(256) void gemm_mfma(
    const float* __restrict__ Xf,
    const unsigned short* __restrict__ Wt,   // bf16 W^T [128][128]
    unsigned short* __restrict__ Y)          // bf16 out [N][128]
{
    __shared__ unsigned short Wl[4 * 8 * 64 * 8];   // 32 KB, frag order

    const int tid  = threadIdx.x;
    const int wave = tid >> 6;
    const int lane = tid & 63;

    for (int s = tid; s < 2048; s += 256) {
        const int ln  = s & 63;
        const int ntk = s >> 6;           // kt*8 + nt
        const int nt  = ntk & 7;
        const int kt  = ntk >> 3;
        const int n   = nt * 16 + (ln & 15);
        const int k   = kt * 32 + (ln >> 4) * 8;
        *(uint4*)(&Wl[s * 8]) = *(const uint4*)(Wt + n * F + k);
    }
    __syncthreads();

    const int m     = blockIdx.x * 64 + wave * 16 + (lane & 15);
    const bool mval = (m < N_NODES);
    const int kq    = (lane >> 4) * 8;

    f32x4 acc[8] = {};

#pragma unroll
    for (int kt = 0; kt < 4; ++kt) {
        ABFrag a;
        if (mval) {
            const float* p = Xf + (size_t)m * F + kt * 32 + kq;
            const float4 u0 = *(const float4*)p;
            const float4 u1 = *(const float4*)(p + 4);
            a.u[0] = f2bf(u0.x); a.u[1] = f2bf(u0.y);
            a.u[2] = f2bf(u0.z); a.u[3] = f2bf(u0.w);
            a.u[4] = f2bf(u1.x); a.u[5] = f2bf(u1.y);
            a.u[6] = f2bf(u1.z); a.u[7] = f2bf(u1.w);
        } else {
            a.q = make_uint4(0, 0, 0, 0);
        }
#pragma unroll
        for (int nt = 0; nt < 8; ++nt) {
            ABFrag b;
            b.q = *(const uint4*)(&Wl[((kt * 8 + nt) * 64 + lane) * 8]);
            acc[nt] = __builtin_amdgcn_mfma_f32_16x16x32_bf16(a.v, b.v, acc[nt], 0, 0, 0);
        }
    }

    const int rbase = blockIdx.x * 64 + wave * 16 + (lane >> 4) * 4;
    const int cbase = lane & 15;
#pragma unroll
    for (int r = 0; r < 4; ++r) {
        const int row = rbase + r;
        if (row < N_NODES) {
#pragma unroll
            for (int nt = 0; nt < 8; ++nt) {
                Y[(size_t)row * F + nt * 16 + cbase] = f2bf(acc[nt][r]);
            }
        }
    }
}

// ---------------- Fused SpMM -> relu -> GEMM (interior layers) -------------
// Block = 16 rows. Gather -> relu -> LDS A-tile -> each wave computes a 16x32
// slice with 8 MFMA, B-frags straight from L2-resident Wt.
// A-tile pad 132 shorts: 4-way read banks (R8: conflicts 400K->200K).
__global__ __launch_bounds__(256) void spmm_gemm_fused(
    const unsigned short* __restrict__ Xb,   // gather source (prev layer X@W, raw)
    const int* __restrict__ row_ptr,
    const unsigned int* __restrict__ pairs,
    const unsigned short* __restrict__ Wt,   // bf16 W^T [128][128]
    unsigned short* __restrict__ Y)          // bf16 out [N][128], raw X@W
{
    __shared__ unsigned short Al[16][132];   // 16-row A-tile, pad -> 4-way banks

    const int tid = threadIdx.x;
    const int l16 = tid & 15;            // lane within quarter-wave
    const int q   = tid >> 4;            // row slot 0..15
    const int row = blockIdx.x * 16 + q;

    float a[8] = {};
    gather_accum(Xb, pairs, row_ptr[row], row_ptr[row + 1], l16, a);

    // relu + bf16 pack -> LDS A-tile
    uint4 o;
    o.x = (unsigned int)f2bf(fmaxf(a[0], 0.f)) | ((unsigned int)f2bf(fmaxf(a[1], 0.f)) << 16);
    o.y = (unsigned int)f2bf(fmaxf(a[2], 0.f)) | ((unsigned int)f2bf(fmaxf(a[3], 0.f)) << 16);
    o.z = (unsigned int)f2bf(fmaxf(a[4], 0.f)) | ((unsigned int)f2bf(fmaxf(a[5], 0.f)) << 16);
    o.w = (unsigned int)f2bf(fmaxf(a[6], 0.f)) | ((unsigned int)f2bf(fmaxf(a[7], 0.f)) << 16);
    *(uint4*)(&Al[q][l16 * 8]) = o;
    __syncthreads();

    // GEMM: wave w covers output cols [w*32, w*32+32)
    const int wave = tid >> 6;
    const int lane = tid & 63;
    const int kq   = (lane >> 4) * 8;
    const int arow = lane & 15;

    f32x4 acc[2] = {};
#pragma unroll
    for (int kt = 0; kt < 4; ++kt) {
        ABFrag af;
        af.q = *(const uint4*)(&Al[arow][kt * 32 + kq]);
#pragma unroll
        for (int nt = 0; nt < 2; ++nt) {
            const int n = wave * 32 + nt * 16 + (lane & 15);
            ABFrag bf_;
            bf_.q = *(const uint4*)(Wt + n * F + kt * 32 + kq);
            acc[nt] = __builtin_amdgcn_mfma_f32_16x16x32_bf16(af.v, bf_.v, acc[nt], 0, 0, 0);
        }
    }

    // C/D layout: col = lane&15, row = (lane>>4)*4 + r
    const int rbase = blockIdx.x * 16 + (lane >> 4) * 4;
    const int cbase = wave * 32 + (lane & 15);
#pragma unroll
    for (int nt = 0; nt < 2; ++nt) {
#pragma unroll
        for (int r = 0; r < 4; ++r) {
            Y[(size_t)(rbase + r) * F + cbase + nt * 16] = f2bf(acc[nt][r]);
        }
    }
}

// ---------------- CSR SpMM (final layer: relu + f32 store) ----------------
__global__ __launch_bounds__(256) void spmm_csr_final(
    const unsigned short* __restrict__ Xb,
    const int* __restrict__ row_ptr,
    const unsigned int* __restrict__ pairs,
    float* __restrict__ Of) {
    const int tid = threadIdx.x;
    const int l16 = tid & 15;            // lane within quarter-wave
    const int q   = tid >> 4;            // quarter index 0..15
    const int row = blockIdx.x * 16 + q;

    float a[8] = {};
    gather_accum(Xb, pairs, row_ptr[row], row_ptr[row + 1], l16, a);

    float4 o0 = {fmaxf(a[0], 0.f), fmaxf(a[1], 0.f), fmaxf(a[2], 0.f), fmaxf(a[3], 0.f)};
    float4 o1 = {fmaxf(a[4], 0.f), fmaxf(a[5], 0.f), fmaxf(a[6], 0.f), fmaxf(a[7], 0.f)};
    float* p = Of + (size_t)row * F + l16 * 8;
    *(float4*)p = o0;
    *(float4*)(p + 4) = o1;
}

// ---------------- launch ----------------

extern "C" void kernel_launch(void* const* d_in, const int* in_sizes, int n_in,
                              void* d_out, int out_size, void* d_ws, size_t ws_size,
                              hipStream_t stream) {
    const float* x    = (const float*)d_in[0];
    const int*   erow = (const int*)d_in[1];
    const int*   ecol = (const int*)d_in[2];
    const float* ew   = (const float*)d_in[3];
    const float* w1   = (const float*)d_in[4];
    const float* w2   = (const float*)d_in[5];
    const float* w3   = (const float*)d_in[6];
    float* out = (float*)d_out;

    char* ws = (char*)d_ws;
    size_t off = 0;
    auto alloc = [&](size_t bytes) -> char* {
        char* p = ws + off;
        off += (bytes + 255) & ~(size_t)255;
        return p;
    };
    unsigned short* bufA = (unsigned short*)alloc((size_t)N_NODES * F * 2); // 25.6 MB
    unsigned short* bufB = (unsigned short*)alloc((size_t)N_NODES * F * 2); // 25.6 MB
    unsigned int* pairs  = (unsigned int*)alloc((size_t)N_EDGES * 4);       // 6.4 MB
    int* counts  = (int*)alloc((size_t)N_NODES * sizeof(int));
    int* row_ptr = (int*)alloc(((size_t)N_NODES + 1) * sizeof(int));
    int* bsums   = (int*)alloc((size_t)SCAN_NB * sizeof(int));
    int* boffs   = (int*)alloc((size_t)SCAN_NB * sizeof(int));
    unsigned short* wt1 = (unsigned short*)alloc((size_t)F * F * 2);
    unsigned short* wt2 = (unsigned short*)alloc((size_t)F * F * 2);
    unsigned short* wt3 = (unsigned short*)alloc((size_t)F * F * 2);

    // Aliasing (all CSR-build scratch dies before the GEMM/SpMM chain):
    //  - cb (25.6 MB) in bufA: consumed by chunk_rank before g1 writes bufA.
    //  - rec (12.8 MB) in bufB: consumed by csr_fill_sharded before fused1
    //    writes bufB.
    unsigned char* cb = (unsigned char*)bufA;
    unsigned long long* rec = (unsigned long long*)bufB;

    // --- CSR build (once; reused by all 3 layers). Zero global atomics. ---
    chunk_hist<<<NCHUNK * 2, 256, 0, stream>>>(erow, cb);
    chunk_prefix<<<((N_NODES / 4) * 8 + 255) / 256, 256, 0, stream>>>(cb, counts);
    scan_block_sums<<<SCAN_NB, SCAN_B, 0, stream>>>(counts, bsums);
    scan_bsums<<<1, 128, 0, stream>>>(bsums, boffs);
    scan_final<<<SCAN_NB, SCAN_B, 0, stream>>>(counts, boffs, row_ptr);
    chunk_rank<<<NCHUNK * 2, 256, 0, stream>>>(erow, ecol, ew, cb, row_ptr, rec);
    csr_fill_sharded<<<(N_EDGES / 256) * NSHARD, 256, 0, stream>>>(rec, pairs);

    // --- Weight transposes to bf16 (single dispatch) ---
    transpose_w_bf16<<<192, 256, 0, stream>>>(w1, w2, w3, wt1, wt2, wt3);

    const int ggrid = (N_NODES + 63) / 64;   // 1563
    const int sgrid = N_NODES / 16;          // 6250 exact

    // Layer 1 GEMM: bufA = x @ w1
    gemm_mfma<<<ggrid, 256, 0, stream>>>(x, wt1, bufA);
    // Fused: bufB = relu(spmm(bufA)) @ w2
    spmm_gemm_fused<<<sgrid, 256, 0, stream>>>(bufA, row_ptr, pairs, wt2, bufB);
    // Fused: bufA = relu(spmm(bufB)) @ w3
    spmm_gemm_fused<<<sgrid, 256, 0, stream>>>(bufB, row_ptr, pairs, wt3, bufA);
    // Final: out = relu(spmm(bufA))
    spmm_csr_final<<<sgrid, 256, 0, stream>>>(bufA, row_ptr, pairs, out);
}